// Round 3
// baseline (2005.945 us; speedup 1.0000x reference)
//
#include <hip/hip_runtime.h>
#include <stdint.h>

// Workspace layout (float offsets)
#define WS_M2 0          // 16384 floats  (512 x 32)
#define WS_N2 16384      // 2048  floats  (64 x 32)
#define WS_WT 18432      // 131072 floats (32 x 4096), W transposed: Wt[r*4096+o]
#define WS_Z  149504     // 32768 floats  (1024 x 32)

// ---------------------------------------------------------------------------
// Kernel A: collapse TT factor chains into small dense matrices. (unchanged)
// ---------------------------------------------------------------------------
__global__ __launch_bounds__(256) void precompute_kernel(
    const float* __restrict__ f0, const float* __restrict__ f1,
    const float* __restrict__ f2, const float* __restrict__ f3,
    const float* __restrict__ f4, const float* __restrict__ g0,
    const float* __restrict__ g1, const float* __restrict__ g2,
    float* __restrict__ ws)
{
    __shared__ float sA[8192];
    const int t = threadIdx.x;
    const int blk = blockIdx.x;
    if (blk < 8) {
        for (int i = t; i < 2048; i += 256) {
            int a01 = i >> 5, r2 = i & 31;
            int a0 = a01 >> 3, a1 = a01 & 7;
            float s = 0.f;
            #pragma unroll
            for (int r1 = 0; r1 < 32; ++r1)
                s += f0[a0*32 + r1] * f1[r1*256 + a1*32 + r2];
            sA[i] = s;
        }
        __syncthreads();
        for (int i = t; i < 2048; i += 256) {
            int a012 = blk*64 + (i >> 5), r3 = i & 31;
            int a01 = a012 >> 3, a2 = a012 & 7;
            float s = 0.f;
            #pragma unroll
            for (int r2 = 0; r2 < 32; ++r2)
                s += sA[a01*32 + r2] * f2[r2*256 + a2*32 + r3];
            ws[WS_M2 + a012*32 + r3] = s;
        }
    } else if (blk == 8) {
        for (int i = t; i < 2048; i += 256) {
            int a34 = i >> 5, s2 = i & 31;
            int a3 = a34 >> 3, a4 = a34 & 7;
            float s = 0.f;
            #pragma unroll
            for (int s1 = 0; s1 < 32; ++s1)
                s += f3[a3*32 + s1] * f4[s1*256 + a4*32 + s2];
            ws[WS_N2 + i] = s;
        }
    } else {
        const int j = blk - 9;   // 0..31, o-slice
        for (int i = t; i < 8192; i += 256) {
            int o01 = i >> 5, q = i & 31;
            int o0 = o01 >> 4, o1 = o01 & 15;
            float s = 0.f;
            #pragma unroll
            for (int p = 0; p < 32; ++p)
                s += g0[o0*32 + p] * g1[p*512 + o1*32 + q];
            sA[i] = s;
        }
        __syncthreads();
        for (int i = t; i < 4096; i += 256) {
            int o = j*128 + (i >> 5);
            int r = i & 31;
            int o01 = o >> 4, o2 = o & 15;
            float s = 0.f;
            #pragma unroll
            for (int q = 0; q < 32; ++q)
                s += sA[o01*32 + q] * g2[q*512 + o2*32 + r];
            ws[WS_WT + r*4096 + o] = s;
        }
    }
}

// ---------------------------------------------------------------------------
// Kernel B v3: v1 skeleton (k-split, barrier-free phase 1, per-lane global
// dword x loads with 8-deep prefetch, acc[32]) with ONE change:
//   M2 no longer read per-k from global (s_load latency drain). Each wave
//   double-buffers its own 32k x 32r M2 chunk (4 KB) in its private LDS
//   region, T14 style: issue the 4 float4 loads for chunk c+1 at the top of
//   iteration c, ds_write them after chunk c's compute. Wave-local, no
//   barriers. Inner loop M2 reads are conflict-free broadcast ds_read_b128
//   (in-order lgkmcnt); x loads are the only vmcnt stream -> both pipeline.
// LDS regions (per wave, stride 2080 floats, same as v1's partials pitch):
//   during k-loop : wave w's M2 dbuf at buf[w*2080 .. w*2080+2048)
//   after k-loop  : wave w's partials  at buf[w*2080 + r*65 + m] (aliases ONLY
//                   its own dead chunk buffer -> no extra barrier needed)
//   after reduce  : T3t in w=0 region, N2 at [4160..6208), T5 at [6240..7264)
// LDS: 8320 + 512 floats = ~35 KB -> 4 blocks/CU.
// ---------------------------------------------------------------------------
__global__ __launch_bounds__(256, 4) void main_kernel(
    const float* __restrict__ x, const float* __restrict__ core,
    const float* __restrict__ ws, float* __restrict__ zout)
{
    __shared__ float buf[8320];
    __shared__ float spart[512];
    const int t = threadIdx.x;
    const int b = blockIdx.x;
    const int w    = __builtin_amdgcn_readfirstlane(t >> 6);  // wave id 0..3
    const int lane = t & 63;                                   // = m

    const float* __restrict__ xw  = x + (size_t)b * 32768 + w * 8192 + lane;
    const float* __restrict__ m2g = ws + WS_M2 + w * 4096;  // wave's k-quarter
    float* __restrict__ mb = buf + w * 2080;                // wave-private dbuf

    // ---- prologue: stage M2 chunk 0 (32k x 32r = 1024 floats) into mb[0..1024)
    {
        const float4* s4 = (const float4*)m2g;
        float4* d4 = (float4*)mb;
        float4 v0 = s4[lane], v1 = s4[lane+64], v2 = s4[lane+128], v3 = s4[lane+192];
        d4[lane] = v0; d4[lane+64] = v1; d4[lane+128] = v2; d4[lane+192] = v3;
    }

    float acc[32];
    #pragma unroll
    for (int r = 0; r < 32; ++r) acc[r] = 0.f;

    for (int c = 0; c < 4; ++c) {
        // issue-early: loads for chunk c+1 (latency hides under compute below)
        float4 n0, n1, n2, n3;
        if (c < 3) {
            const float4* s4 = (const float4*)(m2g + (c+1)*1024);
            n0 = s4[lane]; n1 = s4[lane+64]; n2 = s4[lane+128]; n3 = s4[lane+192];
        }
        // compute chunk c: 32 k's, x per-lane from global, M2 broadcast from LDS
        const float* __restrict__ m2c = mb + (c & 1) * 1024;
        #pragma unroll
        for (int k0 = 0; k0 < 32; k0 += 8) {
            float xv[8];
            #pragma unroll
            for (int i = 0; i < 8; ++i) xv[i] = xw[(c*32 + k0 + i) * 64];
            #pragma unroll
            for (int i = 0; i < 8; ++i) {
                const float* __restrict__ mr = m2c + (k0 + i) * 32;
                #pragma unroll
                for (int r = 0; r < 32; ++r) acc[r] += xv[i] * mr[r];
            }
        }
        // write-late: chunk c+1 into the other buffer (wave-local ordering)
        if (c < 3) {
            float4* d4 = (float4*)(mb + ((c+1) & 1) * 1024);
            d4[lane] = n0; d4[lane+64] = n1; d4[lane+128] = n2; d4[lane+192] = n3;
        }
    }

    // write per-wave partial, transposed with pitch 65 (conflict-free);
    // aliases ONLY this wave's own (dead) M2 chunk buffer -> no barrier needed
    #pragma unroll
    for (int r = 0; r < 32; ++r) buf[w*2080 + r*65 + lane] = acc[r];
    __syncthreads();

    // ---- reduce over the 4 k-quarters; final T3t lands in w=0 region
    {
        const int rr = t >> 3;         // 0..31
        const int mb2 = (t & 7) * 8;   // 0,8,...,56
        float s[8];
        #pragma unroll
        for (int i = 0; i < 8; ++i) {
            s[i] = buf[rr*65 + mb2 + i] + buf[2080 + rr*65 + mb2 + i]
                 + buf[4160 + rr*65 + mb2 + i] + buf[6240 + rr*65 + mb2 + i];
        }
        // each thread writes only addresses it alone read -> no barrier needed
        #pragma unroll
        for (int i = 0; i < 8; ++i) buf[rr*65 + mb2 + i] = s[i];
    }
    __syncthreads();

    // ---- stage N2 into [4160..6208)
    {
        const float4* n24 = (const float4*)(ws + WS_N2);
        float4* d = (float4*)(buf + 4160);
        d[t] = n24[t];
        d[256 + t] = n24[256 + t];
    }
    __syncthreads();

    // ---- phase 3: T5[r3,s2] = sum_m T3t[r3,m] * N2[m,s2] -> [6240..7264)
    {
        const int r3  = t >> 3;
        const int s2b = (t & 7) * 4;
        float a0=0.f, a1=0.f, a2=0.f, a3=0.f;
        #pragma unroll 8
        for (int m = 0; m < 64; ++m) {
            float av = buf[r3*65 + m];
            const float* n = &buf[4160 + m*32 + s2b];
            a0 += av*n[0]; a1 += av*n[1]; a2 += av*n[2]; a3 += av*n[3];
        }
        float* d = &buf[6240 + r3*32 + s2b];
        d[0]=a0; d[1]=a1; d[2]=a2; d[3]=a3;
    }
    __syncthreads();

    // ---- phase 4: z[ro] = sum_k T5[k] * core[k,ro]
    {
        const int ro2 = t & 15;
        const int kc  = t >> 4;
        const float2* core2 = (const float2*)core;
        float s0 = 0.f, s1 = 0.f;
        const int k0 = kc * 64;
        for (int k = k0; k < k0 + 64; ++k) {
            float tv = buf[6240 + k];
            float2 cv = core2[k*16 + ro2];
            s0 += tv*cv.x; s1 += tv*cv.y;
        }
        spart[kc*32 + ro2*2 + 0] = s0;
        spart[kc*32 + ro2*2 + 1] = s1;
    }
    __syncthreads();
    if (t < 32) {
        float s = 0.f;
        #pragma unroll
        for (int kc = 0; kc < 16; ++kc) s += spart[kc*32 + t];
        zout[b*32 + t] = s;
    }
}

// ---------------------------------------------------------------------------
// Kernel C: out[b,o] = sum_r z[b,r]*Wt[r,o] + bias[o]  (unchanged)
// ---------------------------------------------------------------------------
__global__ __launch_bounds__(256) void out_kernel(
    const float* __restrict__ ws, const float* __restrict__ bias,
    float* __restrict__ out)
{
    __shared__ float sW[8192];   // Wt tile [32][256]
    __shared__ float sZt[2176];  // z tile transposed [32 ro][68]
    __shared__ float sB[256];
    const int t  = threadIdx.x;
    const int bt = blockIdx.x;
    const int ot = blockIdx.y;

    {
        const float4* wt4 = (const float4*)(ws + WS_WT);
        float4* d = (float4*)sW;
        #pragma unroll
        for (int i = 0; i < 8; ++i) {
            int idx = i*256 + t;
            int ro = idx >> 6, oc = idx & 63;
            d[idx] = wt4[ro*1024 + ot*64 + oc];
        }
    }
    {
        const float4* z4 = (const float4*)(ws + WS_Z) + bt*512;
        #pragma unroll
        for (int i = 0; i < 2; ++i) {
            int idx = i*256 + t;
            int bl = idx >> 3, r4 = idx & 7;
            float4 v = z4[idx];
            sZt[(r4*4 + 0)*68 + bl] = v.x;
            sZt[(r4*4 + 1)*68 + bl] = v.y;
            sZt[(r4*4 + 2)*68 + bl] = v.z;
            sZt[(r4*4 + 3)*68 + bl] = v.w;
        }
    }
    if (t < 64) {
        const float4* b4 = (const float4*)bias + ot*64;
        ((float4*)sB)[t] = b4[t];
    }
    __syncthreads();

    const int oc = t & 63;
    const int bg = t >> 6;
    const float4* sW4 = (const float4*)sW;
    const float4 bv = ((const float4*)sB)[oc];
    float4* out4 = (float4*)out;

    for (int bi = 0; bi < 16; bi += 4) {
        const int bl = bg*16 + bi;
        float4 a0 = bv, a1 = bv, a2 = bv, a3 = bv;
        #pragma unroll
        for (int ro = 0; ro < 32; ++ro) {
            float4 w = sW4[ro*64 + oc];
            float4 z = *(const float4*)&sZt[ro*68 + bl];
            a0.x += z.x*w.x; a0.y += z.x*w.y; a0.z += z.x*w.z; a0.w += z.x*w.w;
            a1.x += z.y*w.x; a1.y += z.y*w.y; a1.z += z.y*w.z; a1.w += z.y*w.w;
            a2.x += z.z*w.x; a2.y += z.z*w.y; a2.z += z.z*w.z; a2.w += z.z*w.w;
            a3.x += z.w*w.x; a3.y += z.w*w.y; a3.z += z.w*w.z; a3.w += z.w*w.w;
        }
        const size_t obase = (size_t)(bt*64 + bl) * 1024 + ot*64 + oc;
        out4[obase + 0*1024] = a0;
        out4[obase + 1*1024] = a1;
        out4[obase + 2*1024] = a2;
        out4[obase + 3*1024] = a3;
    }
}

extern "C" void kernel_launch(void* const* d_in, const int* in_sizes, int n_in,
                              void* d_out, int out_size, void* d_ws, size_t ws_size,
                              hipStream_t stream)
{
    const float* x    = (const float*)d_in[0];
    const float* f0   = (const float*)d_in[1];
    const float* f1   = (const float*)d_in[2];
    const float* f2   = (const float*)d_in[3];
    const float* f3   = (const float*)d_in[4];
    const float* f4   = (const float*)d_in[5];
    const float* core = (const float*)d_in[6];
    const float* g0   = (const float*)d_in[7];
    const float* g1   = (const float*)d_in[8];
    const float* g2   = (const float*)d_in[9];
    const float* bias = (const float*)d_in[10];
    float* ws  = (float*)d_ws;
    float* out = (float*)d_out;

    precompute_kernel<<<41, 256, 0, stream>>>(f0, f1, f2, f3, f4, g0, g1, g2, ws);
    main_kernel<<<1024, 256, 0, stream>>>(x, core, ws, ws + WS_Z);
    out_kernel<<<dim3(16, 16), 256, 0, stream>>>(ws, bias, out);
}

// Round 4
// 280.202 us; speedup vs baseline: 7.1589x; 7.1589x over previous
//
#include <hip/hip_runtime.h>
#include <stdint.h>

// Workspace layout (float offsets)
#define WS_M2 0          // 16384 floats  (512 x 32)
#define WS_N2 16384      // 2048  floats  (64 x 32)
#define WS_WT 18432      // 131072 floats (32 x 4096), W transposed: Wt[r*4096+o]
#define WS_Z  149504     // 32768 floats  (1024 x 32)

// Direct global->LDS async copy, 16 B per lane. LDS dest is wave-uniform base
// + lane*16; global src is per-lane (must include lane*4 floats).
#define GLOAD_LDS16(gsrc, ldst)                                         \
    __builtin_amdgcn_global_load_lds(                                   \
        (const __attribute__((address_space(1))) uint32_t*)(gsrc),      \
        (__attribute__((address_space(3))) uint32_t*)(ldst), 16, 0, 0)

// ---------------------------------------------------------------------------
// Kernel A: collapse TT factor chains into small dense matrices. (unchanged)
// ---------------------------------------------------------------------------
__global__ __launch_bounds__(256) void precompute_kernel(
    const float* __restrict__ f0, const float* __restrict__ f1,
    const float* __restrict__ f2, const float* __restrict__ f3,
    const float* __restrict__ f4, const float* __restrict__ g0,
    const float* __restrict__ g1, const float* __restrict__ g2,
    float* __restrict__ ws)
{
    __shared__ float sA[8192];
    const int t = threadIdx.x;
    const int blk = blockIdx.x;
    if (blk < 8) {
        for (int i = t; i < 2048; i += 256) {
            int a01 = i >> 5, r2 = i & 31;
            int a0 = a01 >> 3, a1 = a01 & 7;
            float s = 0.f;
            #pragma unroll
            for (int r1 = 0; r1 < 32; ++r1)
                s += f0[a0*32 + r1] * f1[r1*256 + a1*32 + r2];
            sA[i] = s;
        }
        __syncthreads();
        for (int i = t; i < 2048; i += 256) {
            int a012 = blk*64 + (i >> 5), r3 = i & 31;
            int a01 = a012 >> 3, a2 = a012 & 7;
            float s = 0.f;
            #pragma unroll
            for (int r2 = 0; r2 < 32; ++r2)
                s += sA[a01*32 + r2] * f2[r2*256 + a2*32 + r3];
            ws[WS_M2 + a012*32 + r3] = s;
        }
    } else if (blk == 8) {
        for (int i = t; i < 2048; i += 256) {
            int a34 = i >> 5, s2 = i & 31;
            int a3 = a34 >> 3, a4 = a34 & 7;
            float s = 0.f;
            #pragma unroll
            for (int s1 = 0; s1 < 32; ++s1)
                s += f3[a3*32 + s1] * f4[s1*256 + a4*32 + s2];
            ws[WS_N2 + i] = s;
        }
    } else {
        const int j = blk - 9;   // 0..31, o-slice
        for (int i = t; i < 8192; i += 256) {
            int o01 = i >> 5, q = i & 31;
            int o0 = o01 >> 4, o1 = o01 & 15;
            float s = 0.f;
            #pragma unroll
            for (int p = 0; p < 32; ++p)
                s += g0[o0*32 + p] * g1[p*512 + o1*32 + q];
            sA[i] = s;
        }
        __syncthreads();
        for (int i = t; i < 4096; i += 256) {
            int o = j*128 + (i >> 5);
            int r = i & 31;
            int o01 = o >> 4, o2 = o & 15;
            float s = 0.f;
            #pragma unroll
            for (int q = 0; q < 32; ++q)
                s += sA[o01*32 + q] * g2[q*512 + o2*32 + r];
            ws[WS_WT + r*4096 + o] = s;
        }
    }
}

// ---------------------------------------------------------------------------
// Kernel B v4: one block per batch element; r-SPLIT phase 1.
//   Wave w owns r in [8w, 8w+8) over ALL 512 k -> acc = 8 named floats, no
//   cross-wave reduce. Per k: x via lane-varying ds_read_b32 from an LDS
//   x-tile, M2 octet via 2 wave-uniform ds_read_b128 (broadcast, free).
//   x tiles (64k x 64m = 16 KB) and M2 chunks (64k x 32r = 8 KB) are staged
//   with global_load_lds, double-buffered, 2-phase: stage(c+1) -> compute(c)
//   -> __syncthreads (drains vmcnt). 8 chunks of 64 k. The free stage slot
//   at c==7 prefetches N2 into the dead m2buf[0].
// LDS map (floats), s[12288] = 48 KB -> 3 blocks/CU:
//   k-loop:  xbuf0 [0..4096), xbuf1 [4096..8192),
//            m2b0 [8192..10240), m2b1 [10240..12288)
//   after:   T3t (pitch 65) [0..2080)   (xbuf0 dead)
//            N2  [8192..10240)          (staged during c==7, m2b0 dead)
//            T5  [4096..5120)           (xbuf1 dead)
//            spart [5120..5632)
// ---------------------------------------------------------------------------
__global__ __launch_bounds__(256, 3) void main_kernel(
    const float* __restrict__ x, const float* __restrict__ core,
    const float* __restrict__ ws, float* __restrict__ zout)
{
    __shared__ float s[12288];
    const int t = threadIdx.x;
    const int b = blockIdx.x;
    const int w    = __builtin_amdgcn_readfirstlane(t >> 6);  // wave id 0..3
    const int lane = t & 63;                                   // = m

    const float* __restrict__ xb = x + (size_t)b * 32768;

    // ---- prologue: stage chunk 0 (x: 16 KB, M2: 8 KB)
    {
        const float* sx = xb + w*1024 + lane*4;
        float* dx = s + w*1024;
        GLOAD_LDS16(sx,       dx);
        GLOAD_LDS16(sx + 256, dx + 256);
        GLOAD_LDS16(sx + 512, dx + 512);
        GLOAD_LDS16(sx + 768, dx + 768);
        const float* sm = ws + WS_M2 + w*512 + lane*4;
        float* dm = s + 8192 + w*512;
        GLOAD_LDS16(sm,       dm);
        GLOAD_LDS16(sm + 256, dm + 256);
    }
    __syncthreads();

    float a0=0.f, a1=0.f, a2=0.f, a3=0.f, a4=0.f, a5=0.f, a6=0.f, a7=0.f;

    #pragma unroll 1
    for (int c = 0; c < 8; ++c) {
        if (c < 7) {   // stage chunk c+1 into the other buffers
            const float* sx = xb + (c+1)*4096 + w*1024 + lane*4;
            float* dx = s + ((c+1)&1)*4096 + w*1024;
            GLOAD_LDS16(sx,       dx);
            GLOAD_LDS16(sx + 256, dx + 256);
            GLOAD_LDS16(sx + 512, dx + 512);
            GLOAD_LDS16(sx + 768, dx + 768);
            const float* sm = ws + WS_M2 + (c+1)*2048 + w*512 + lane*4;
            float* dm = s + 8192 + ((c+1)&1)*2048 + w*512;
            GLOAD_LDS16(sm,       dm);
            GLOAD_LDS16(sm + 256, dm + 256);
        } else {       // free slot: prefetch N2 into dead m2b0
            const float* sn = ws + WS_N2 + w*512 + lane*4;
            float* dn = s + 8192 + w*512;
            GLOAD_LDS16(sn,       dn);
            GLOAD_LDS16(sn + 256, dn + 256);
        }
        // compute chunk c: 64 k's; 8 FMAs per k into named accumulators
        const float* __restrict__ xt = s + (c&1)*4096;
        const float* __restrict__ mt = s + 8192 + (c&1)*2048 + w*8;
        #pragma unroll 4
        for (int k = 0; k < 64; ++k) {
            float  xv = xt[k*64 + lane];
            float4 ma = *(const float4*)(mt + k*32);
            float4 mb = *(const float4*)(mt + k*32 + 4);
            a0 += xv*ma.x; a1 += xv*ma.y; a2 += xv*ma.z; a3 += xv*ma.w;
            a4 += xv*mb.x; a5 += xv*mb.y; a6 += xv*mb.z; a7 += xv*mb.w;
        }
        __syncthreads();   // all reads of buf[c&1] done; stage vmcnt drained
    }

    // ---- write T3t[r, m] (pitch 65, conflict-free) into dead xbuf0
    {
        const int rb = w*8;
        s[(rb+0)*65 + lane] = a0;
        s[(rb+1)*65 + lane] = a1;
        s[(rb+2)*65 + lane] = a2;
        s[(rb+3)*65 + lane] = a3;
        s[(rb+4)*65 + lane] = a4;
        s[(rb+5)*65 + lane] = a5;
        s[(rb+6)*65 + lane] = a6;
        s[(rb+7)*65 + lane] = a7;
    }
    __syncthreads();   // T3t visible (N2 already drained at loop's last barrier)

    // ---- phase 3: T5[r3,s2] = sum_m T3t[r3,m] * N2[m,s2] -> [4096..5120)
    {
        const int r3  = t >> 3;
        const int s2b = (t & 7) * 4;
        float b0=0.f, b1=0.f, b2=0.f, b3=0.f;
        #pragma unroll 8
        for (int m = 0; m < 64; ++m) {
            float av = s[r3*65 + m];
            const float* n = &s[8192 + m*32 + s2b];
            b0 += av*n[0]; b1 += av*n[1]; b2 += av*n[2]; b3 += av*n[3];
        }
        float* d = &s[4096 + r3*32 + s2b];
        d[0]=b0; d[1]=b1; d[2]=b2; d[3]=b3;
    }
    __syncthreads();

    // ---- phase 4: z[ro] = sum_k T5[k] * core[k,ro]
    {
        const int ro2 = t & 15;
        const int kc  = t >> 4;
        const float2* core2 = (const float2*)core;
        float s0 = 0.f, s1 = 0.f;
        const int k0 = kc * 64;
        for (int k = k0; k < k0 + 64; ++k) {
            float tv = s[4096 + k];
            float2 cv = core2[k*16 + ro2];
            s0 += tv*cv.x; s1 += tv*cv.y;
        }
        s[5120 + kc*32 + ro2*2 + 0] = s0;
        s[5120 + kc*32 + ro2*2 + 1] = s1;
    }
    __syncthreads();
    if (t < 32) {
        float acc = 0.f;
        #pragma unroll
        for (int kc = 0; kc < 16; ++kc) acc += s[5120 + kc*32 + t];
        zout[b*32 + t] = acc;
    }
}

// ---------------------------------------------------------------------------
// Kernel C: out[b,o] = sum_r z[b,r]*Wt[r,o] + bias[o]  (unchanged)
// ---------------------------------------------------------------------------
__global__ __launch_bounds__(256) void out_kernel(
    const float* __restrict__ ws, const float* __restrict__ bias,
    float* __restrict__ out)
{
    __shared__ float sW[8192];   // Wt tile [32][256]
    __shared__ float sZt[2176];  // z tile transposed [32 ro][68]
    __shared__ float sB[256];
    const int t  = threadIdx.x;
    const int bt = blockIdx.x;
    const int ot = blockIdx.y;

    {
        const float4* wt4 = (const float4*)(ws + WS_WT);
        float4* d = (float4*)sW;
        #pragma unroll
        for (int i = 0; i < 8; ++i) {
            int idx = i*256 + t;
            int ro = idx >> 6, oc = idx & 63;
            d[idx] = wt4[ro*1024 + ot*64 + oc];
        }
    }
    {
        const float4* z4 = (const float4*)(ws + WS_Z) + bt*512;
        #pragma unroll
        for (int i = 0; i < 2; ++i) {
            int idx = i*256 + t;
            int bl = idx >> 3, r4 = idx & 7;
            float4 v = z4[idx];
            sZt[(r4*4 + 0)*68 + bl] = v.x;
            sZt[(r4*4 + 1)*68 + bl] = v.y;
            sZt[(r4*4 + 2)*68 + bl] = v.z;
            sZt[(r4*4 + 3)*68 + bl] = v.w;
        }
    }
    if (t < 64) {
        const float4* b4 = (const float4*)bias + ot*64;
        ((float4*)sB)[t] = b4[t];
    }
    __syncthreads();

    const int oc = t & 63;
    const int bg = t >> 6;
    const float4* sW4 = (const float4*)sW;
    const float4 bv = ((const float4*)sB)[oc];
    float4* out4 = (float4*)out;

    for (int bi = 0; bi < 16; bi += 4) {
        const int bl = bg*16 + bi;
        float4 a0 = bv, a1 = bv, a2 = bv, a3 = bv;
        #pragma unroll
        for (int ro = 0; ro < 32; ++ro) {
            float4 w = sW4[ro*64 + oc];
            float4 z = *(const float4*)&sZt[ro*68 + bl];
            a0.x += z.x*w.x; a0.y += z.x*w.y; a0.z += z.x*w.z; a0.w += z.x*w.w;
            a1.x += z.y*w.x; a1.y += z.y*w.y; a1.z += z.y*w.z; a1.w += z.y*w.w;
            a2.x += z.z*w.x; a2.y += z.z*w.y; a2.z += z.z*w.z; a2.w += z.z*w.w;
            a3.x += z.w*w.x; a3.y += z.w*w.y; a3.z += z.w*w.z; a3.w += z.w*w.w;
        }
        const size_t obase = (size_t)(bt*64 + bl) * 1024 + ot*64 + oc;
        out4[obase + 0*1024] = a0;
        out4[obase + 1*1024] = a1;
        out4[obase + 2*1024] = a2;
        out4[obase + 3*1024] = a3;
    }
}

extern "C" void kernel_launch(void* const* d_in, const int* in_sizes, int n_in,
                              void* d_out, int out_size, void* d_ws, size_t ws_size,
                              hipStream_t stream)
{
    const float* x    = (const float*)d_in[0];
    const float* f0   = (const float*)d_in[1];
    const float* f1   = (const float*)d_in[2];
    const float* f2   = (const float*)d_in[3];
    const float* f3   = (const float*)d_in[4];
    const float* f4   = (const float*)d_in[5];
    const float* core = (const float*)d_in[6];
    const float* g0   = (const float*)d_in[7];
    const float* g1   = (const float*)d_in[8];
    const float* g2   = (const float*)d_in[9];
    const float* bias = (const float*)d_in[10];
    float* ws  = (float*)d_ws;
    float* out = (float*)d_out;

    precompute_kernel<<<41, 256, 0, stream>>>(f0, f1, f2, f3, f4, g0, g1, g2, ws);
    main_kernel<<<1024, 256, 0, stream>>>(x, core, ws, ws + WS_Z);
    out_kernel<<<dim3(16, 16), 256, 0, stream>>>(ws, bias, out);
}

// Round 5
// 276.988 us; speedup vs baseline: 7.2420x; 1.0116x over previous
//
#include <hip/hip_runtime.h>
#include <stdint.h>

// Workspace layout (float offsets)
#define WS_M2 0          // 16384 floats  (512 x 32)
#define WS_N2 16384      // 2048  floats  (64 x 32)
#define WS_WT 18432      // 131072 floats (32 x 4096), W transposed: Wt[r*4096+o]
#define WS_Z  149504     // 32768 floats  (1024 x 32)

// Direct global->LDS async copy, 16 B per lane. LDS dest is wave-uniform base
// (HW appends lane*16); global src must include lane*4 floats.
#define GLOAD_LDS16(gsrc, ldst)                                         \
    __builtin_amdgcn_global_load_lds(                                   \
        (const __attribute__((address_space(1))) uint32_t*)(gsrc),      \
        (__attribute__((address_space(3))) uint32_t*)(ldst), 16, 0, 0)

// ---------------------------------------------------------------------------
// Kernel A: collapse TT factor chains into small dense matrices. (unchanged)
// ---------------------------------------------------------------------------
__global__ __launch_bounds__(256) void precompute_kernel(
    const float* __restrict__ f0, const float* __restrict__ f1,
    const float* __restrict__ f2, const float* __restrict__ f3,
    const float* __restrict__ f4, const float* __restrict__ g0,
    const float* __restrict__ g1, const float* __restrict__ g2,
    float* __restrict__ ws)
{
    __shared__ float sA[8192];
    const int t = threadIdx.x;
    const int blk = blockIdx.x;
    if (blk < 8) {
        for (int i = t; i < 2048; i += 256) {
            int a01 = i >> 5, r2 = i & 31;
            int a0 = a01 >> 3, a1 = a01 & 7;
            float s = 0.f;
            #pragma unroll
            for (int r1 = 0; r1 < 32; ++r1)
                s += f0[a0*32 + r1] * f1[r1*256 + a1*32 + r2];
            sA[i] = s;
        }
        __syncthreads();
        for (int i = t; i < 2048; i += 256) {
            int a012 = blk*64 + (i >> 5), r3 = i & 31;
            int a01 = a012 >> 3, a2 = a012 & 7;
            float s = 0.f;
            #pragma unroll
            for (int r2 = 0; r2 < 32; ++r2)
                s += sA[a01*32 + r2] * f2[r2*256 + a2*32 + r3];
            ws[WS_M2 + a012*32 + r3] = s;
        }
    } else if (blk == 8) {
        for (int i = t; i < 2048; i += 256) {
            int a34 = i >> 5, s2 = i & 31;
            int a3 = a34 >> 3, a4 = a34 & 7;
            float s = 0.f;
            #pragma unroll
            for (int s1 = 0; s1 < 32; ++s1)
                s += f3[a3*32 + s1] * f4[s1*256 + a4*32 + s2];
            ws[WS_N2 + i] = s;
        }
    } else {
        const int j = blk - 9;   // 0..31, o-slice
        for (int i = t; i < 8192; i += 256) {
            int o01 = i >> 5, q = i & 31;
            int o0 = o01 >> 4, o1 = o01 & 15;
            float s = 0.f;
            #pragma unroll
            for (int p = 0; p < 32; ++p)
                s += g0[o0*32 + p] * g1[p*512 + o1*32 + q];
            sA[i] = s;
        }
        __syncthreads();
        for (int i = t; i < 4096; i += 256) {
            int o = j*128 + (i >> 5);
            int r = i & 31;
            int o01 = o >> 4, o2 = o & 15;
            float s = 0.f;
            #pragma unroll
            for (int q = 0; q < 32; ++q)
                s += sA[o01*32 + q] * g2[q*512 + o2*32 + r];
            ws[WS_WT + r*4096 + o] = s;
        }
    }
}

// ---------------------------------------------------------------------------
// Kernel B v5: 256 blocks x 512 threads (8 waves); 4 batch elements / block.
//   Wave w owns r-quad [4w, 4w+4) over all 512 k. Per k per wave:
//   ONE wave-uniform ds_read_b128 (M2 quad) + 4 per-lane global dword x loads
//   (8-deep k-groups, v1 pattern) + 16 FMAs into acc[4][4]. M2 (64 KB) and N2
//   are staged into LDS ONCE via global_load_lds -> zero barriers in k-loop.
//   M2 LDS traffic amortized over 4 batches (4x cut vs v4); x never touches
//   the LDS pipe.
// LDS map (floats), s[26752] = 107 KB (1 block/CU):
//   M2  [0..16384)        dead after k-loop -> T5 [0..4096), spart [4096..5120)
//   T3t [16384..24704)    4 batches x pitch-65 (2080 each)
//   N2  [24704..26752)
// ---------------------------------------------------------------------------
__global__ __launch_bounds__(512, 2) void main_kernel(
    const float* __restrict__ x, const float* __restrict__ core,
    const float* __restrict__ ws, float* __restrict__ zout)
{
    __shared__ float s[26752];
    const int t = threadIdx.x;
    const int b0 = blockIdx.x * 4;
    const int w    = __builtin_amdgcn_readfirstlane(t >> 6);  // wave id 0..7
    const int lane = t & 63;                                   // = m

    // ---- stage M2 (16384 floats) + N2 (2048 floats) into LDS, once
    {
        const float* sm = ws + WS_M2 + w*2048 + lane*4;
        float* dm = s + w*2048;
        #pragma unroll
        for (int i = 0; i < 8; ++i)
            GLOAD_LDS16(sm + i*256, dm + i*256);
        const float* sn = ws + WS_N2 + w*256 + lane*4;
        GLOAD_LDS16(sn, s + 24704 + w*256);
    }
    __syncthreads();   // drains global_load_lds vmcnt

    // ---- phase 1: T3[b][m][r-quad] accumulation, no barriers
    float acc[4][4];
    #pragma unroll
    for (int bb = 0; bb < 4; ++bb)
        #pragma unroll
        for (int rr = 0; rr < 4; ++rr) acc[bb][rr] = 0.f;

    const float* xp0 = x + (size_t)(b0+0) * 32768 + lane;
    const float* xp1 = x + (size_t)(b0+1) * 32768 + lane;
    const float* xp2 = x + (size_t)(b0+2) * 32768 + lane;
    const float* xp3 = x + (size_t)(b0+3) * 32768 + lane;
    const float* mq  = s + w*4;   // wave's M2 quad column base

    #pragma unroll 1
    for (int k0 = 0; k0 < 512; k0 += 8) {
        float xv[4][8];
        #pragma unroll
        for (int i = 0; i < 8; ++i) {
            xv[0][i] = xp0[i*64];
            xv[1][i] = xp1[i*64];
            xv[2][i] = xp2[i*64];
            xv[3][i] = xp3[i*64];
        }
        xp0 += 512; xp1 += 512; xp2 += 512; xp3 += 512;
        #pragma unroll
        for (int i = 0; i < 8; ++i) {
            float4 m4 = *(const float4*)(mq + (k0 + i)*32);
            #pragma unroll
            for (int bb = 0; bb < 4; ++bb) {
                acc[bb][0] += xv[bb][i]*m4.x;
                acc[bb][1] += xv[bb][i]*m4.y;
                acc[bb][2] += xv[bb][i]*m4.z;
                acc[bb][3] += xv[bb][i]*m4.w;
            }
        }
    }

    // ---- write T3t[b][r][m], pitch 65 (conflict-free), r = 4w+rr
    #pragma unroll
    for (int bb = 0; bb < 4; ++bb)
        #pragma unroll
        for (int rr = 0; rr < 4; ++rr)
            s[16384 + bb*2080 + (w*4 + rr)*65 + lane] = acc[bb][rr];
    __syncthreads();

    // ---- phase 3: T5[b][r3][s2] = sum_m T3t[b][r3][m] * N2[m][s2]
    //      thread: bb = t>>7, r3 = (t>>2)&31, s2 octet = (t&3)*8
    {
        const int bb  = t >> 7;
        const int r3  = (t >> 2) & 31;
        const int s2o = (t & 3) * 8;
        float a[8];
        #pragma unroll
        for (int i = 0; i < 8; ++i) a[i] = 0.f;
        const float* t3 = s + 16384 + bb*2080 + r3*65;
        const float* n2 = s + 24704 + s2o;
        #pragma unroll 8
        for (int m = 0; m < 64; ++m) {
            float av = t3[m];
            const float* n = n2 + m*32;
            #pragma unroll
            for (int i = 0; i < 8; ++i) a[i] += av * n[i];
        }
        float* d = s + bb*1024 + r3*32 + s2o;   // T5 over dead M2 region
        #pragma unroll
        for (int i = 0; i < 8; ++i) d[i] = a[i];
    }
    __syncthreads();

    // ---- phase 4: z[b][ro] = sum_k T5[b][k] * core[k][ro]
    //      thread: bb = t>>7, kc = (t>>4)&7 (128-k chunk), ro2 = t&15 (2 ro)
    {
        const int bb  = t >> 7;
        const int kc  = (t >> 4) & 7;
        const int ro2 = t & 15;
        const float2* core2 = (const float2*)core;
        float s0 = 0.f, s1 = 0.f;
        const int k0 = kc * 128;
        for (int k = k0; k < k0 + 128; ++k) {
            float tv = s[bb*1024 + k];
            float2 cv = core2[k*16 + ro2];
            s0 += tv*cv.x; s1 += tv*cv.y;
        }
        s[4096 + bb*256 + kc*32 + ro2*2 + 0] = s0;
        s[4096 + bb*256 + kc*32 + ro2*2 + 1] = s1;
    }
    __syncthreads();
    if (t < 128) {
        const int bb = t >> 5;
        const int ro = t & 31;
        float acc2 = 0.f;
        #pragma unroll
        for (int kc = 0; kc < 8; ++kc) acc2 += s[4096 + bb*256 + kc*32 + ro];
        zout[(b0 + bb)*32 + ro] = acc2;
    }
}

// ---------------------------------------------------------------------------
// Kernel C: out[b,o] = sum_r z[b,r]*Wt[r,o] + bias[o]  (unchanged)
// ---------------------------------------------------------------------------
__global__ __launch_bounds__(256) void out_kernel(
    const float* __restrict__ ws, const float* __restrict__ bias,
    float* __restrict__ out)
{
    __shared__ float sW[8192];   // Wt tile [32][256]
    __shared__ float sZt[2176];  // z tile transposed [32 ro][68]
    __shared__ float sB[256];
    const int t  = threadIdx.x;
    const int bt = blockIdx.x;
    const int ot = blockIdx.y;

    {
        const float4* wt4 = (const float4*)(ws + WS_WT);
        float4* d = (float4*)sW;
        #pragma unroll
        for (int i = 0; i < 8; ++i) {
            int idx = i*256 + t;
            int ro = idx >> 6, oc = idx & 63;
            d[idx] = wt4[ro*1024 + ot*64 + oc];
        }
    }
    {
        const float4* z4 = (const float4*)(ws + WS_Z) + bt*512;
        #pragma unroll
        for (int i = 0; i < 2; ++i) {
            int idx = i*256 + t;
            int bl = idx >> 3, r4 = idx & 7;
            float4 v = z4[idx];
            sZt[(r4*4 + 0)*68 + bl] = v.x;
            sZt[(r4*4 + 1)*68 + bl] = v.y;
            sZt[(r4*4 + 2)*68 + bl] = v.z;
            sZt[(r4*4 + 3)*68 + bl] = v.w;
        }
    }
    if (t < 64) {
        const float4* b4 = (const float4*)bias + ot*64;
        ((float4*)sB)[t] = b4[t];
    }
    __syncthreads();

    const int oc = t & 63;
    const int bg = t >> 6;
    const float4* sW4 = (const float4*)sW;
    const float4 bv = ((const float4*)sB)[oc];
    float4* out4 = (float4*)out;

    for (int bi = 0; bi < 16; bi += 4) {
        const int bl = bg*16 + bi;
        float4 a0 = bv, a1 = bv, a2 = bv, a3 = bv;
        #pragma unroll
        for (int ro = 0; ro < 32; ++ro) {
            float4 w = sW4[ro*64 + oc];
            float4 z = *(const float4*)&sZt[ro*68 + bl];
            a0.x += z.x*w.x; a0.y += z.x*w.y; a0.z += z.x*w.z; a0.w += z.x*w.w;
            a1.x += z.y*w.x; a1.y += z.y*w.y; a1.z += z.y*w.z; a1.w += z.y*w.w;
            a2.x += z.z*w.x; a2.y += z.z*w.y; a2.z += z.z*w.z; a2.w += z.z*w.w;
            a3.x += z.w*w.x; a3.y += z.w*w.y; a3.z += z.w*w.z; a3.w += z.w*w.w;
        }
        const size_t obase = (size_t)(bt*64 + bl) * 1024 + ot*64 + oc;
        out4[obase + 0*1024] = a0;
        out4[obase + 1*1024] = a1;
        out4[obase + 2*1024] = a2;
        out4[obase + 3*1024] = a3;
    }
}

extern "C" void kernel_launch(void* const* d_in, const int* in_sizes, int n_in,
                              void* d_out, int out_size, void* d_ws, size_t ws_size,
                              hipStream_t stream)
{
    const float* x    = (const float*)d_in[0];
    const float* f0   = (const float*)d_in[1];
    const float* f1   = (const float*)d_in[2];
    const float* f2   = (const float*)d_in[3];
    const float* f3   = (const float*)d_in[4];
    const float* f4   = (const float*)d_in[5];
    const float* core = (const float*)d_in[6];
    const float* g0   = (const float*)d_in[7];
    const float* g1   = (const float*)d_in[8];
    const float* g2   = (const float*)d_in[9];
    const float* bias = (const float*)d_in[10];
    float* ws  = (float*)d_ws;
    float* out = (float*)d_out;

    precompute_kernel<<<41, 256, 0, stream>>>(f0, f1, f2, f3, f4, g0, g1, g2, ws);
    main_kernel<<<256, 512, 0, stream>>>(x, core, ws, ws + WS_Z);
    out_kernel<<<dim3(16, 16), 256, 0, stream>>>(ws, bias, out);
}